// Round 5
// baseline (2291.034 us; speedup 1.0000x reference)
//
#include <hip/hip_runtime.h>
#include <hip/hip_bf16.h>

// CascadedAttention on MI355X — round 4.
// vs round 3: P2's tanh had 2 trans ops (exp2+rcp). Factor e^{2(UaH+WaS)} =
// E*D with E = e^{2 UaH} precomputed in the GEMM epilogue (fp16, saturating:
// inf->tanh=1, 0->tanh=-1 exact) and D = e^{2 WaS} (16 exp2/lane/step).
// P2 inner: {fma_mix(E,D), +1, rcp, fmac} = 1 trans/elem. Also: Wa in
// registers (not LDS), h as packed h2 + register hPrev, P4 h2 reads,
// 2-row pairing in P2 for shuffle-chain ILP.

typedef _Float16 h8 __attribute__((ext_vector_type(8)));
typedef _Float16 h4 __attribute__((ext_vector_type(4)));
typedef _Float16 h2 __attribute__((ext_vector_type(2)));
typedef float    f4 __attribute__((ext_vector_type(4)));
typedef float    f2 __attribute__((ext_vector_type(2)));

#define B_   256
#define T_   150
#define F_   1024
#define U_   28
#define TU3  84   // 3*U

#define C2LOG2E 2.8853900817779268f   // 2*log2(e)
#define LOG2E   1.4426950408889634f

__device__ __forceinline__ float fast_exp(float x) {
    return __builtin_amdgcn_exp2f(x * LOG2E);
}
__device__ __forceinline__ float fast_sigmoid(float x) {
    float e = __builtin_amdgcn_exp2f(-x * LOG2E);
    return __builtin_amdgcn_rcpf(1.0f + e);
}
__device__ __forceinline__ float fast_tanh(float x) {
    float e = __builtin_amdgcn_exp2f(x * C2LOG2E);
    float r = __builtin_amdgcn_rcpf(e + 1.0f);
    return 1.0f - 2.0f * r;
}

// ---------------- fp32 -> fp16 convert ----------------
__global__ void k_cvt(const float* __restrict__ in, _Float16* __restrict__ out, int n4) {
    int i = blockIdx.x * blockDim.x + threadIdx.x;
    int stride = gridDim.x * blockDim.x;
    const f4* in4 = (const f4*)in;
    h4* out4 = (h4*)out;
    for (; i < n4; i += stride) {
        f4 v = in4[i];
        h4 o;
        o[0] = (_Float16)v[0]; o[1] = (_Float16)v[1];
        o[2] = (_Float16)v[2]; o[3] = (_Float16)v[3];
        out4[i] = o;
    }
}

// ---------------- Ua (1024x1024) -> fp16 transposed ----------------
__global__ void k_cvt_transpose(const float* __restrict__ in, _Float16* __restrict__ out) {
    int idx = blockIdx.x * blockDim.x + threadIdx.x;
    int r = idx >> 10, c = idx & 1023;
    out[(c << 10) + r] = (_Float16)in[idx];
}

// ------- GEMM: E = exp2(clamp(C2*( x_h @ Ua + Ba2))) (M=38400,N=1024,K=1024) -------
#define BM 128
#define BN 128
#define BK 32
#define LDT 40

__global__ __launch_bounds__(256) void k_gemm(
    const _Float16* __restrict__ A,
    const _Float16* __restrict__ Bt,
    const float*    __restrict__ bias,
    _Float16*       __restrict__ C)     // E, fp16 (saturating exp of 2*UaH)
{
    __shared__ _Float16 As[BM][LDT];
    __shared__ _Float16 Bs[BN][LDT];
    const int K = 1024;
    int bm = blockIdx.y, bn = blockIdx.x;
    int tid = threadIdx.x;
    int lane = tid & 63, wid = tid >> 6;
    int wm = wid >> 1, wn = wid & 1;
    f4 acc[4][4];
#pragma unroll
    for (int i = 0; i < 4; i++)
#pragma unroll
        for (int j = 0; j < 4; j++) { f4 z = {0.f, 0.f, 0.f, 0.f}; acc[i][j] = z; }

    int row0 = bm * BM, col0 = bn * BN;
    for (int kt = 0; kt < K; kt += BK) {
#pragma unroll
        for (int p = 0; p < 2; ++p) {
            int s = tid + p * 256;
            int r = s >> 2, seg = s & 3;
            h8 va = *(const h8*)(A  + (size_t)(row0 + r) * K + kt + seg * 8);
            *(h8*)(&As[r][seg * 8]) = va;
            h8 vb = *(const h8*)(Bt + (size_t)(col0 + r) * K + kt + seg * 8);
            *(h8*)(&Bs[r][seg * 8]) = vb;
        }
        __syncthreads();
        int kq = (lane >> 4) * 8;
        h8 af[4], bf[4];
#pragma unroll
        for (int mi = 0; mi < 4; mi++) af[mi] = *(const h8*)(&As[wm * 64 + mi * 16 + (lane & 15)][kq]);
#pragma unroll
        for (int ni = 0; ni < 4; ni++) bf[ni] = *(const h8*)(&Bs[wn * 64 + ni * 16 + (lane & 15)][kq]);
#pragma unroll
        for (int mi = 0; mi < 4; mi++)
#pragma unroll
            for (int ni = 0; ni < 4; ni++)
                acc[mi][ni] = __builtin_amdgcn_mfma_f32_16x16x32_f16(af[mi], bf[ni], acc[mi][ni], 0, 0, 0);
        __syncthreads();
    }
    int rq = (lane >> 4) * 4, cq = lane & 15;
#pragma unroll
    for (int mi = 0; mi < 4; mi++)
#pragma unroll
        for (int ni = 0; ni < 4; ni++) {
            int gc = col0 + wn * 64 + ni * 16 + cq;
            float bv = bias[gc];
#pragma unroll
            for (int j = 0; j < 4; j++) {
                int gr = row0 + wm * 64 + mi * 16 + rq + j;
                // E = 2^(min(2*log2e*uah, 15.8)); 2^15.8 = 57053 < fp16 max.
                float ex = __builtin_amdgcn_exp2f(fminf(C2LOG2E * (acc[mi][ni][j] + bv), 15.8f));
                C[(size_t)gr * 1024 + gc] = (_Float16)ex;
            }
        }
}

// ---------------- GEMM: XG = x_h @ gk (M=38400, N=84 pad 96, K=1024), fp16 out ---------
#define XLD 72

__global__ __launch_bounds__(256) void k_gemm_xg(
    const _Float16* __restrict__ A,
    const float*    __restrict__ gk,
    _Float16*       __restrict__ C)
{
    __shared__ _Float16 As[128][XLD];
    __shared__ _Float16 Bs[96][XLD];
    int tid = threadIdx.x;
    int lane = tid & 63, wid = tid >> 6;
    int wm = wid >> 1, wn = wid & 1;
    int row0 = blockIdx.x * 128;
    f4 acc[4][3];
#pragma unroll
    for (int i = 0; i < 4; i++)
#pragma unroll
        for (int j = 0; j < 3; j++) { f4 z = {0.f, 0.f, 0.f, 0.f}; acc[i][j] = z; }

    if (tid < 432) { h2 z; z[0] = (_Float16)0.f; z[1] = (_Float16)0.f; ((h2*)&Bs[84][0])[tid] = z; }

    for (int kt = 0; kt < 1024; kt += 64) {
#pragma unroll
        for (int p = 0; p < 4; ++p) {
            int s = tid + p * 256;
            int r = s >> 3, seg = s & 7;
            *(h8*)(&As[r][seg * 8]) = *(const h8*)(A + (size_t)(row0 + r) * 1024 + kt + seg * 8);
        }
#pragma unroll
        for (int p = 0; p < 21; ++p) {
            int s = tid + p * 256;
            int j = s % 84, k = s / 84;
            Bs[j][k] = (_Float16)gk[(size_t)(kt + k) * 84 + j];
        }
        __syncthreads();
#pragma unroll
        for (int kk = 0; kk < 64; kk += 32) {
            int kq = kk + (lane >> 4) * 8;
            h8 af[4], bf[3];
#pragma unroll
            for (int mi = 0; mi < 4; mi++) af[mi] = *(const h8*)(&As[wm * 64 + mi * 16 + (lane & 15)][kq]);
#pragma unroll
            for (int ni = 0; ni < 3; ni++) bf[ni] = *(const h8*)(&Bs[wn * 48 + ni * 16 + (lane & 15)][kq]);
#pragma unroll
            for (int mi = 0; mi < 4; mi++)
#pragma unroll
                for (int ni = 0; ni < 3; ni++)
                    acc[mi][ni] = __builtin_amdgcn_mfma_f32_16x16x32_f16(af[mi], bf[ni], acc[mi][ni], 0, 0, 0);
        }
        __syncthreads();
    }
    int rq = (lane >> 4) * 4, cq = lane & 15;
#pragma unroll
    for (int mi = 0; mi < 4; mi++)
#pragma unroll
        for (int ni = 0; ni < 3; ni++) {
            int gc = wn * 48 + ni * 16 + cq;
            if (gc < 84) {
#pragma unroll
                for (int j = 0; j < 4; j++) {
                    int gr = row0 + wm * 64 + mi * 16 + rq + j;
                    C[(size_t)gr * 84 + gc] = (_Float16)acc[mi][ni][j];
                }
            }
        }
}

// ---------------- recurrence: one WG (1024 thr) per batch, 150 steps ----------------
__global__ __launch_bounds__(1024) void k_recur3(
    const _Float16* __restrict__ Eg,   // [B][T][F] fp16: e^{2 UaH}, saturating
    const _Float16* __restrict__ xg,   // [B][T][84] fp16
    const float* __restrict__ Wa,      // [U][F]
    const float* __restrict__ Va,      // [F]
    const float* __restrict__ Ba1,     // [F]
    const float* __restrict__ grk,     // [U][3U]
    const float* __restrict__ gbias,   // [2][3U]
    float* __restrict__ out)           // [B][T][U]
{
    __shared__ h2    sXG2[T_ * 42];        // 25.2 KB  (h2 over j-pairs)
    __shared__ float sWaS[F_];             // 4 KB
    __shared__ float sScore[160];          // p_r = exp(score_r), unnormalized
    __shared__ f2    sPart2[16 * 42];      // 5.4 KB   (16 r-groups x 42 j-pairs)
    __shared__ h2    sGrkT[TU3 * 14];      // 4.7 KB   [j][k] = (grk[2k][j], grk[2k+1][j])
    __shared__ float sHz[TU3];
    __shared__ h2    sH2[14];              // h state packed pairs
    __shared__ float sDen;

    int b = blockIdx.x;
    int tid = threadIdx.x;
    int lane = tid & 63, wvid = tid >> 6;  // 16 waves

    // ---- one-time loads
    {
        const h2* xgb = (const h2*)(xg + (size_t)b * T_ * TU3);
        for (int i = tid; i < T_ * 42; i += 1024) sXG2[i] = xgb[i];
    }
    for (int i = tid; i < TU3 * 14; i += 1024) {
        int j = i / 14, k = i - j * 14;
        h2 g; g[0] = (_Float16)grk[(2 * k) * TU3 + j]; g[1] = (_Float16)grk[(2 * k + 1) * TU3 + j];
        sGrkT[i] = g;
    }
    if (tid < 14) { h2 z; z[0] = (_Float16)0.f; z[1] = (_Float16)0.f; sH2[tid] = z; }

    // Wa column for this thread's f=tid, packed over u-pairs: 14 x h2 registers
    h2 wreg[14];
#pragma unroll
    for (int k = 0; k < 14; ++k) {
        h2 w; w[0] = (_Float16)Wa[(2 * k) * F_ + tid]; w[1] = (_Float16)Wa[(2 * k + 1) * F_ + tid];
        wreg[k] = w;
    }
    float rBa1 = Ba1[tid];
    // rA = -2*Va for this lane's 16 f's; vaBase = sum of those Va
    float rA0[8], rA1[8], vaBase = 0.f;
    {
        f4 a0 = *(const f4*)(Va + 8 * lane);
        f4 a1 = *(const f4*)(Va + 8 * lane + 4);
        f4 b0 = *(const f4*)(Va + 512 + 8 * lane);
        f4 b1 = *(const f4*)(Va + 512 + 8 * lane + 4);
#pragma unroll
        for (int e = 0; e < 4; ++e) {
            rA0[e] = -2.f * a0[e]; rA0[4 + e] = -2.f * a1[e];
            rA1[e] = -2.f * b0[e]; rA1[4 + e] = -2.f * b1[e];
            vaBase += a0[e] + a1[e] + b0[e] + b1[e];
        }
    }
    int p4g = tid / 42, p4j = tid - p4g * 42;      // r-group, j-pair
    bool p4on = tid < 16 * 42;                     // threads 0..671
    bool denon = (wvid == 13);
    bool hzon = (tid >= 896) && (tid < 896 + TU3);
    int hj = tid - 896;
    float rGb1 = hzon ? gbias[TU3 + hj] : 0.f;
    float rG0 = 0.f, rG1 = 0.f, rG2 = 0.f;
    if (tid < U_) { rG0 = gbias[tid]; rG1 = gbias[U_ + tid]; rG2 = gbias[2 * U_ + tid]; }
    float hPrev = 0.f;                             // h state (lanes 0..27 of wave 0)
    __syncthreads();

    const _Float16* ub = Eg + (size_t)b * T_ * F_;
    float* ob = out + (size_t)b * T_ * U_;

    for (int t = 0; t < T_; ++t) {
        // ---- hh: current h as 14 h2 (broadcast)
        h2 hh[14];
#pragma unroll
        for (int k = 0; k < 14; ++k) hh[k] = sH2[k];
        // ---- P1: WaS[f] = Ba1[f] + h . Wa[:,f]  (Wa in registers, mix-fma)
        {
            float acc = rBa1;
#pragma unroll
            for (int k = 0; k < 14; ++k) {
                acc = fmaf((float)hh[k][0], (float)wreg[k][0], acc);
                acc = fmaf((float)hh[k][1], (float)wreg[k][1], acc);
            }
            sWaS[tid] = acc;
        }
        __syncthreads();   // B1
        // ---- P1b: D = e^{2 WaS} for this lane's 16 f's
        float rD0[8], rD1[8];
        {
            f4 a0 = *(const f4*)(sWaS + 8 * lane);
            f4 a1 = *(const f4*)(sWaS + 8 * lane + 4);
            f4 b0 = *(const f4*)(sWaS + 512 + 8 * lane);
            f4 b1 = *(const f4*)(sWaS + 512 + 8 * lane + 4);
#pragma unroll
            for (int e = 0; e < 4; ++e) {
                rD0[e]     = __builtin_amdgcn_exp2f(C2LOG2E * a0[e]);
                rD0[4 + e] = __builtin_amdgcn_exp2f(C2LOG2E * a1[e]);
                rD1[e]     = __builtin_amdgcn_exp2f(C2LOG2E * b0[e]);
                rD1[4 + e] = __builtin_amdgcn_exp2f(C2LOG2E * b1[e]);
            }
        }
        // ---- P2: p_r = exp(score_r); inner {mix-mul, +1, rcp, fmac}; 2 rows/iter
        {
            int r = wvid;
            for (; r + 16 < T_; r += 32) {
                const h8* p1 = (const h8*)(ub + (size_t)r * F_);
                const h8* p2 = (const h8*)(ub + (size_t)(r + 16) * F_);
                h8 a0 = p1[lane], a1 = p1[64 + lane];
                h8 b0 = p2[lane], b1 = p2[64 + lane];
                float s1 = vaBase, s2 = vaBase;
#pragma unroll
                for (int e = 0; e < 8; ++e) {
                    float m0 = fmaf((float)a0[e], rD0[e], 0.f);
                    s1 = fmaf(rA0[e], __builtin_amdgcn_rcpf(1.0f + m0), s1);
                    float m1 = fmaf((float)a1[e], rD1[e], 0.f);
                    s1 = fmaf(rA1[e], __builtin_amdgcn_rcpf(1.0f + m1), s1);
                    float n0 = fmaf((float)b0[e], rD0[e], 0.f);
                    s2 = fmaf(rA0[e], __builtin_amdgcn_rcpf(1.0f + n0), s2);
                    float n1 = fmaf((float)b1[e], rD1[e], 0.f);
                    s2 = fmaf(rA1[e], __builtin_amdgcn_rcpf(1.0f + n1), s2);
                }
#pragma unroll
                for (int off = 32; off; off >>= 1) {
                    s1 += __shfl_xor(s1, off, 64);
                    s2 += __shfl_xor(s2, off, 64);
                }
                if (lane == 0) {
                    sScore[r]      = fast_exp(s1);
                    sScore[r + 16] = fast_exp(s2);
                }
            }
            if (r < T_) {
                const h8* p1 = (const h8*)(ub + (size_t)r * F_);
                h8 a0 = p1[lane], a1 = p1[64 + lane];
                float s1 = vaBase;
#pragma unroll
                for (int e = 0; e < 8; ++e) {
                    float m0 = fmaf((float)a0[e], rD0[e], 0.f);
                    s1 = fmaf(rA0[e], __builtin_amdgcn_rcpf(1.0f + m0), s1);
                    float m1 = fmaf((float)a1[e], rD1[e], 0.f);
                    s1 = fmaf(rA1[e], __builtin_amdgcn_rcpf(1.0f + m1), s1);
                }
#pragma unroll
                for (int off = 32; off; off >>= 1) s1 += __shfl_xor(s1, off, 64);
                if (lane == 0) sScore[r] = fast_exp(s1);
            }
        }
        __syncthreads();   // B2
        // ---- P4: xz partials (p . XG, h2 pairs) + denominator + hz
        if (p4on) {
            float acc0 = 0.f, acc1 = 0.f;
            for (int r = p4g; r < T_; r += 16) {
                h2 m2 = sXG2[r * 42 + p4j];
                float s = sScore[r];
                acc0 = fmaf((float)m2[0], s, acc0);
                acc1 = fmaf((float)m2[1], s, acc1);
            }
            f2 pv; pv[0] = acc0; pv[1] = acc1;
            sPart2[p4g * 42 + p4j] = pv;
        }
        if (denon) {
            float d0 = (lane < T_)       ? sScore[lane]       : 0.f;
            float d1 = (lane + 64 < T_)  ? sScore[lane + 64]  : 0.f;
            float d2 = (lane + 128 < T_) ? sScore[lane + 128] : 0.f;
            float ds = d0 + d1 + d2;
#pragma unroll
            for (int off = 32; off; off >>= 1) ds += __shfl_xor(ds, off, 64);
            if (lane == 0) sDen = ds;
        }
        if (hzon) {
            float hz = rGb1;
#pragma unroll
            for (int k = 0; k < 14; ++k) {
                h2 g = sGrkT[hj * 14 + k];
                hz = fmaf((float)hh[k][0], (float)g[0], hz);
                hz = fmaf((float)hh[k][1], (float)g[1], hz);
            }
            sHz[hj] = hz;
        }
        __syncthreads();   // B4
        // ---- P5: gates + state + output (threads 0..27, wave 0)
        float hn = 0.f;
        if (tid < U_) {
            const float* sp = (const float*)sPart2;
            float rs = __builtin_amdgcn_rcpf(sDen);
            float x0 = 0.f, x1 = 0.f, x2 = 0.f;
#pragma unroll
            for (int c = 0; c < 16; ++c) {
                x0 += sp[c * 84 + tid];
                x1 += sp[c * 84 + U_ + tid];
                x2 += sp[c * 84 + 2 * U_ + tid];
            }
            x0 = fmaf(x0, rs, rG0);
            x1 = fmaf(x1, rs, rG1);
            x2 = fmaf(x2, rs, rG2);
            float z  = fast_sigmoid(x0 + sHz[tid]);
            float r  = fast_sigmoid(x1 + sHz[U_ + tid]);
            float hhat = fast_tanh(x2 + r * sHz[2 * U_ + tid]);
            hn = z * hPrev + (1.f - z) * hhat;
            hPrev = hn;
            ob[(size_t)t * U_ + tid] = hn;
        }
        if (wvid == 0) {
            float other = __shfl_xor(hn, 1, 64);
            if (tid < U_ && !(tid & 1)) {
                h2 hv; hv[0] = (_Float16)hn; hv[1] = (_Float16)other;
                sH2[tid >> 1] = hv;
            }
        }
        __syncthreads();   // B5
    }
}

extern "C" void kernel_launch(void* const* d_in, const int* in_sizes, int n_in,
                              void* d_out, int out_size, void* d_ws, size_t ws_size,
                              hipStream_t stream) {
    (void)in_sizes; (void)n_in; (void)out_size; (void)ws_size;
    const float* x   = (const float*)d_in[0];
    const float* Wa  = (const float*)d_in[1];
    const float* Ua  = (const float*)d_in[2];
    const float* Va  = (const float*)d_in[3];
    const float* Ba1 = (const float*)d_in[4];
    const float* Ba2 = (const float*)d_in[5];
    // d_in[6] = Ba3: softmax shift-invariant, dropped.
    const float* gk  = (const float*)d_in[7];
    const float* grk = (const float*)d_in[8];
    const float* gb  = (const float*)d_in[9];
    float* out = (float*)d_out;

    const size_t NX = (size_t)B_ * T_ * F_;
    _Float16* xh  = (_Float16*)d_ws;
    _Float16* uat = xh + NX;
    _Float16* eg  = uat + (size_t)F_ * F_;   // E = e^{2 UaH}
    _Float16* xgh = eg + NX;

    k_cvt<<<2048, 256, 0, stream>>>(x, xh, (int)(NX / 4));
    k_cvt_transpose<<<(F_ * F_) / 256, 256, 0, stream>>>(Ua, uat);
    dim3 gg(F_ / BN, (B_ * T_) / BM);
    k_gemm<<<gg, 256, 0, stream>>>(xh, uat, Ba2, eg);
    k_gemm_xg<<<(B_ * T_) / 128, 256, 0, stream>>>(xh, gk, xgh);
    k_recur3<<<B_, 1024, 0, stream>>>(eg, xgh, Wa, Va, Ba1, grk, gb, out);
}